// Round 8
// baseline (604.037 us; speedup 1.0000x reference)
//
#include <hip/hip_runtime.h>
#include <math.h>

#define NROWS 16384
#define GATES 5
#define HDIM 512

using bf16x8 = __attribute__((ext_vector_type(8))) short;
using f32x4  = __attribute__((ext_vector_type(4))) float;

__device__ inline float b2f(unsigned short s) {
  unsigned int u = ((unsigned int)s) << 16;
  return __builtin_bit_cast(float, u);
}
__device__ inline unsigned short f2b(float f) {
  unsigned int u = __builtin_bit_cast(unsigned int, f);
  u += 0x7fffu + ((u >> 16) & 1u);   // RNE
  return (unsigned short)(u >> 16);
}

// fast activations: v_exp_f32 (2^x) + v_rcp_f32, ~5 inst, saturate correctly
__device__ inline float fast_sigmoid(float x) {
  float t = __builtin_amdgcn_exp2f(-1.4426950408889634f * x);
  return __builtin_amdgcn_rcpf(1.0f + t);
}
__device__ inline float fast_tanh(float x) {
  float t = __builtin_amdgcn_exp2f(2.8853900817779268f * x);
  return 1.0f - 2.0f * __builtin_amdgcn_rcpf(1.0f + t);
}

__device__ inline void gload_lds16(const unsigned short* g, unsigned short* l) {
  __builtin_amdgcn_global_load_lds(
      (const __attribute__((address_space(1))) unsigned int*)(g),
      (__attribute__((address_space(3))) unsigned int*)(l), 16, 0, 0);
}

// ---------------- packing / conversion kernels (f32 -> bf16) ----------------

__global__ void pack_x(const float* __restrict__ word,
                       const float* __restrict__ tag,
                       const float* __restrict__ rel,
                       unsigned short* __restrict__ xcat) {
  int idx = blockIdx.x * 256 + threadIdx.x;       // N*512
  int n = idx >> 9, c = idx & 511;
  float v = 0.f;
  if (c < 300)      v = word[n * 300 + c];
  else if (c < 350) v = tag[n * 50 + (c - 300)];
  else if (c < 400) v = rel[n * 50 + (c - 350)];
  xcat[idx] = f2b(v);
}

__global__ void pack_w(const float* __restrict__ Ww,
                       const float* __restrict__ Wt,
                       const float* __restrict__ Wr,
                       unsigned short* __restrict__ Wcat) {
  int idx = blockIdx.x * 256 + threadIdx.x;       // G*512*512
  int gh = idx >> 9;                              // g*512 + h
  int c = idx & 511;
  float v = 0.f;
  if (c < 300)      v = Ww[gh * 300 + c];
  else if (c < 350) v = Wt[gh * 50 + (c - 300)];
  else if (c < 400) v = Wr[gh * 50 + (c - 350)];
  Wcat[idx] = f2b(v);
}

__global__ void cvt_bf16(const float* __restrict__ in,
                         unsigned short* __restrict__ out, int n) {
  int i = (blockIdx.x * 256 + threadIdx.x) * 4;
  if (i >= n) return;
  float4 v = *(const float4*)(in + i);
  ushort4 o;
  o.x = f2b(v.x); o.y = f2b(v.y); o.z = f2b(v.z); o.w = f2b(v.w);
  *(ushort4*)(out + i) = o;
}

__global__ void pack_bias(const float* __restrict__ bw, const float* __restrict__ bt,
                          const float* __restrict__ br, const float* __restrict__ bh,
                          const float* __restrict__ bl, const float* __restrict__ bhp,
                          const float* __restrict__ bk,
                          float* bias0, float* bias1, float* bias2, float* biasD) {
  int i = blockIdx.x * 256 + threadIdx.x;         // G*512
  if (i < GATES * HDIM) {
    bias0[i] = bw[i] + bt[i] + br[i];
    bias1[i] = bh[i];
    bias2[i] = bl[i];
    biasD[i] = bhp[i] + bk[i];
  }
}

// ---------------- fused 4-layer MLP+gate kernel -----------------------------
// Block = 64 rows x 1 gate, 512 threads (8 waves x 64 cols each).
// slab[64][512] bf16 (64 KB, XOR-swizzled: phys 16B-slot = slot ^ (row&7)).
// Per layer: A-frags from slab (ds_read_b128), B-frags streamed from global
// (W is L2-resident; each W element read once per block), acc 4x4 f32x4.
// h written back IN-PLACE (full output lives in acc before writeback).
// L3 result (m) never leaves registers: acc = tanh(acc)+biasD, then the two
// gate GEMMs (hprev, k staged into the dead slab) accumulate on top.
// No barriers inside layers -> compiler pipelines B-loads across MFMAs.

__global__ __launch_bounds__(512, 4) void fused_mlp(
    const unsigned short* __restrict__ xcat,
    const unsigned short* __restrict__ hprevb,
    const unsigned short* __restrict__ kb,
    const unsigned short* __restrict__ W0,   // [G][512][512] each
    const unsigned short* __restrict__ Wh,
    const unsigned short* __restrict__ Wl,
    const unsigned short* __restrict__ Whp,
    const unsigned short* __restrict__ Wk,
    const float* __restrict__ bias0, const float* __restrict__ bias1,
    const float* __restrict__ bias2, const float* __restrict__ biasD,
    unsigned short* __restrict__ gates)
{
  __shared__ __align__(16) unsigned short slab[64 * 512];   // 64 KB

  const int t  = threadIdx.x;
  const int g  = blockIdx.x >> 8;          // gate slow dim: round ~= one gate
  const int row0 = (blockIdx.x & 255) * 64;
  const int l  = t & 63;
  const int fr = l & 15, q = l >> 4;
  const int wcol = (t >> 6) * 64;          // wave's 64-col slice
  const size_t wslab = (size_t)g * HDIM * HDIM;

  // ---- stage 64x512 global rows into swizzled slab (dst byte = t*16 + j*8192)
  auto stage = [&](const unsigned short* src) {
#pragma unroll
    for (int j = 0; j < 8; ++j) {
      const int r = j * 8 + (t >> 6);
      const int p = t & 63;
      gload_lds16(src + (size_t)(row0 + r) * HDIM + ((p ^ (r & 7)) * 8),
                  &slab[r * HDIM + p * 8]);
    }
  };

  f32x4 acc[4][4];
  auto initacc = [&](const float* bias) {
#pragma unroll
    for (int ni = 0; ni < 4; ++ni) {
      const float b = bias[g * HDIM + wcol + ni * 16 + fr];
#pragma unroll
      for (int mi = 0; mi < 4; ++mi)
        acc[mi][ni] = (f32x4){b, b, b, b};
    }
  };

  // ---- one GEMM layer: acc += slab @ Wg^T   (K=512, 16 chunks of 32)
  auto layer = [&](const unsigned short* Wg) {
#pragma unroll
    for (int kk8 = 0; kk8 < 64; kk8 += 4) {   // 16B-slot base per chunk
      bf16x8 af[4], bfv[4];
#pragma unroll
      for (int mi = 0; mi < 4; ++mi) {
        const int row = mi * 16 + fr;
        af[mi] = *reinterpret_cast<const bf16x8*>(
            &slab[row * HDIM + (((kk8 + q) ^ (fr & 7)) * 8)]);
      }
#pragma unroll
      for (int ni = 0; ni < 4; ++ni)
        bfv[ni] = *reinterpret_cast<const bf16x8*>(
            Wg + (size_t)(wcol + ni * 16 + fr) * HDIM + (kk8 + q) * 8);
#pragma unroll
      for (int mi = 0; mi < 4; ++mi)
#pragma unroll
        for (int ni = 0; ni < 4; ++ni)
          acc[mi][ni] = __builtin_amdgcn_mfma_f32_16x16x32_bf16(af[mi], bfv[ni], acc[mi][ni], 0, 0, 0);
    }
  };

  // ---- tanh(acc) -> bf16 -> slab, in-place (C/D: col=lane&15, row=q*4+j)
  auto writeslab = [&]() {
#pragma unroll
    for (int mi = 0; mi < 4; ++mi)
#pragma unroll
      for (int ni = 0; ni < 4; ++ni)
#pragma unroll
        for (int j = 0; j < 4; ++j) {
          const int row = mi * 16 + q * 4 + j;
          const int col = wcol + ni * 16 + fr;
          slab[row * HDIM + (((col >> 3) ^ (row & 7)) * 8) + (col & 7)] =
              f2b(fast_tanh(acc[mi][ni][j]));
        }
  };

  // ---------------- pipeline ----------------
  stage(xcat);
  asm volatile("s_waitcnt vmcnt(0)" ::: "memory");
  __syncthreads();

  initacc(bias0);
  layer(W0 + wslab);                 // h0 pre-act in acc
  __syncthreads();                   // all slab reads done
  writeslab();                       // slab = h0
  __syncthreads();

  initacc(bias1);
  layer(Wh + wslab);                 // h1 pre-act
  __syncthreads();
  writeslab();                       // slab = h1
  __syncthreads();

  initacc(bias2);
  layer(Wl + wslab);                 // m pre-act in acc
  {                                  // acc = tanh(acc) + biasD  (m stays in regs)
#pragma unroll
    for (int ni = 0; ni < 4; ++ni) {
      const float bd = biasD[g * HDIM + wcol + ni * 16 + fr];
#pragma unroll
      for (int mi = 0; mi < 4; ++mi)
#pragma unroll
        for (int j = 0; j < 4; ++j)
          acc[mi][ni][j] = fast_tanh(acc[mi][ni][j]) + bd;
    }
  }
  __syncthreads();                   // h1 reads done; slab is dead

  stage(hprevb);
  asm volatile("s_waitcnt vmcnt(0)" ::: "memory");
  __syncthreads();
  layer(Whp + wslab);                // acc += hprev @ Whp^T
  __syncthreads();

  stage(kb);
  asm volatile("s_waitcnt vmcnt(0)" ::: "memory");
  __syncthreads();
  layer(Wk + wslab);                 // acc += k @ Wk^T

  // ---- final gate activation + global write
  unsigned short* outg = gates + (size_t)g * NROWS * HDIM;
#pragma unroll
  for (int mi = 0; mi < 4; ++mi)
#pragma unroll
    for (int ni = 0; ni < 4; ++ni)
#pragma unroll
      for (int j = 0; j < 4; ++j) {
        const int row = row0 + mi * 16 + q * 4 + j;
        const int col = wcol + ni * 16 + fr;
        float v = acc[mi][ni][j];
        v = (g < 4) ? fast_sigmoid(v) : fast_tanh(v);
        outg[(size_t)row * HDIM + col] = f2b(v);
      }
}

// ---------------- final elementwise combine (f32 q/c_prev, f32 out) ----------------

__device__ inline float exb(const uint4& v, int j) {
  unsigned int wd = ((const unsigned int*)&v)[j >> 1];
  return b2f((unsigned short)(wd >> ((j & 1) * 16)));
}

__global__ void combine(const unsigned short* __restrict__ gates,
                        const float* __restrict__ q,
                        const float* __restrict__ cp,
                        float* __restrict__ out) {
  const size_t NM = (size_t)NROWS * HDIM;
  size_t i8 = ((size_t)blockIdx.x * 256 + threadIdx.x) * 8;
  if (i8 >= NM) return;
  uint4 gi = *(const uint4*)(gates + 0 * NM + i8);
  uint4 gf = *(const uint4*)(gates + 1 * NM + i8);
  uint4 gl = *(const uint4*)(gates + 2 * NM + i8);
  uint4 go = *(const uint4*)(gates + 3 * NM + i8);
  uint4 gu = *(const uint4*)(gates + 4 * NM + i8);
  float4 q0 = *(const float4*)(q + i8);
  float4 q1 = *(const float4*)(q + i8 + 4);
  float4 p0 = *(const float4*)(cp + i8);
  float4 p1 = *(const float4*)(cp + i8 + 4);
  float qv[8] = {q0.x, q0.y, q0.z, q0.w, q1.x, q1.y, q1.z, q1.w};
  float pv[8] = {p0.x, p0.y, p0.z, p0.w, p1.x, p1.y, p1.z, p1.w};
  float hv[8], cv[8];
#pragma unroll
  for (int j = 0; j < 8; ++j) {
    float c = exb(gi, j) * exb(gu, j) + exb(gf, j) * qv[j] + exb(gl, j) * pv[j];
    hv[j] = exb(go, j) * fast_tanh(c);
    cv[j] = c;
  }
  *(float4*)(out + i8)      = make_float4(hv[0], hv[1], hv[2], hv[3]);
  *(float4*)(out + i8 + 4)  = make_float4(hv[4], hv[5], hv[6], hv[7]);
  *(float4*)(out + NM + i8)     = make_float4(cv[0], cv[1], cv[2], cv[3]);
  *(float4*)(out + NM + i8 + 4) = make_float4(cv[4], cv[5], cv[6], cv[7]);
}

// ---------------- launch ----------------

extern "C" void kernel_launch(void* const* d_in, const int* in_sizes, int n_in,
                              void* d_out, int out_size, void* d_ws, size_t ws_size,
                              hipStream_t stream) {
  const float* word  = (const float*)d_in[0];
  const float* tag   = (const float*)d_in[1];
  const float* rel   = (const float*)d_in[2];
  const float* kin   = (const float*)d_in[3];
  const float* qin   = (const float*)d_in[4];
  const float* hprev = (const float*)d_in[5];
  const float* cprev = (const float*)d_in[6];
  const float* Ww    = (const float*)d_in[7];
  const float* bw    = (const float*)d_in[8];
  const float* Wt    = (const float*)d_in[9];
  const float* bt    = (const float*)d_in[10];
  const float* Wr    = (const float*)d_in[11];
  const float* br    = (const float*)d_in[12];
  const float* Wh    = (const float*)d_in[13];
  const float* bh    = (const float*)d_in[14];
  const float* Wl    = (const float*)d_in[15];
  const float* bl    = (const float*)d_in[16];
  const float* Whp   = (const float*)d_in[17];
  const float* bhp   = (const float*)d_in[18];
  const float* Wk    = (const float*)d_in[19];
  const float* bk    = (const float*)d_in[20];

  char* ws = (char*)d_ws;
  unsigned short* xcat   = (unsigned short*)(ws);                 // 16,777,216 B
  unsigned short* Wcat   = (unsigned short*)(ws + 16777216);      //  2,621,440 B
  unsigned short* Whb    = (unsigned short*)(ws + 19398656);      //  2,621,440 B
  unsigned short* Wlb    = (unsigned short*)(ws + 22020096);      //  2,621,440 B
  unsigned short* Whpb   = (unsigned short*)(ws + 24641536);      //  2,621,440 B
  unsigned short* Wkb    = (unsigned short*)(ws + 27262976);      //  2,621,440 B
  unsigned short* hprevb = (unsigned short*)(ws + 29884416);      // 16,777,216 B
  unsigned short* kb16   = (unsigned short*)(ws + 46661632);      // 16,777,216 B
  float* bias0           = (float*)(ws + 63438848);               //     10,240 B
  float* bias1           = (float*)(ws + 63449088);
  float* bias2           = (float*)(ws + 63459328);
  float* biasD           = (float*)(ws + 63469568);
  unsigned short* gatesb = (unsigned short*)(ws + 63479808);      // 83,886,080 B

  pack_x<<<32768, 256, 0, stream>>>(word, tag, rel, xcat);
  pack_w<<<5120, 256, 0, stream>>>(Ww, Wt, Wr, Wcat);
  cvt_bf16<<<1280, 256, 0, stream>>>(Wh, Whb, 1310720);
  cvt_bf16<<<1280, 256, 0, stream>>>(Wl, Wlb, 1310720);
  cvt_bf16<<<1280, 256, 0, stream>>>(Whp, Whpb, 1310720);
  cvt_bf16<<<1280, 256, 0, stream>>>(Wk, Wkb, 1310720);
  cvt_bf16<<<8192, 256, 0, stream>>>(hprev, hprevb, 8388608);
  cvt_bf16<<<8192, 256, 0, stream>>>(kin, kb16, 8388608);
  pack_bias<<<10, 256, 0, stream>>>(bw, bt, br, bh, bl, bhp, bk, bias0, bias1, bias2, biasD);

  // fused: blocks = gate (slow) x 256 row-tiles of 64
  fused_mlp<<<GATES * 256, 512, 0, stream>>>(
      xcat, hprevb, kb16, Wcat, Whb, Wlb, Whpb, Wkb,
      bias0, bias1, bias2, biasD, gatesb);

  // c = i*u + f_down*q + f_left*c_prev ; h = o*tanh(c)
  combine<<<4096, 256, 0, stream>>>(gatesb, qin, cprev, (float*)d_out);
}

// Round 9
// 514.041 us; speedup vs baseline: 1.1751x; 1.1751x over previous
//
#include <hip/hip_runtime.h>
#include <math.h>

#define NROWS 16384
#define GATES 5
#define HDIM 512

using bf16x8 = __attribute__((ext_vector_type(8))) short;
using f32x4  = __attribute__((ext_vector_type(4))) float;

__device__ inline float b2f(unsigned short s) {
  unsigned int u = ((unsigned int)s) << 16;
  return __builtin_bit_cast(float, u);
}
__device__ inline unsigned short f2b(float f) {
  unsigned int u = __builtin_bit_cast(unsigned int, f);
  u += 0x7fffu + ((u >> 16) & 1u);   // RNE
  return (unsigned short)(u >> 16);
}

__device__ inline float fast_sigmoid(float x) {
  float t = __builtin_amdgcn_exp2f(-1.4426950408889634f * x);
  return __builtin_amdgcn_rcpf(1.0f + t);
}
__device__ inline float fast_tanh(float x) {
  float t = __builtin_amdgcn_exp2f(2.8853900817779268f * x);
  return 1.0f - 2.0f * __builtin_amdgcn_rcpf(1.0f + t);
}

__device__ inline void gload_lds16(const unsigned short* g, unsigned short* l) {
  __builtin_amdgcn_global_load_lds(
      (const __attribute__((address_space(1))) unsigned int*)(g),
      (__attribute__((address_space(3))) unsigned int*)(l), 16, 0, 0);
}

// ---------------- packing / conversion kernels (f32 -> bf16) ----------------

__global__ void pack_x(const float* __restrict__ word,
                       const float* __restrict__ tag,
                       const float* __restrict__ rel,
                       unsigned short* __restrict__ xcat) {
  int idx = blockIdx.x * 256 + threadIdx.x;       // N*512
  int n = idx >> 9, c = idx & 511;
  float v = 0.f;
  if (c < 300)      v = word[n * 300 + c];
  else if (c < 350) v = tag[n * 50 + (c - 300)];
  else if (c < 400) v = rel[n * 50 + (c - 350)];
  xcat[idx] = f2b(v);
}

__global__ void pack_w(const float* __restrict__ Ww,
                       const float* __restrict__ Wt,
                       const float* __restrict__ Wr,
                       unsigned short* __restrict__ Wcat) {
  int idx = blockIdx.x * 256 + threadIdx.x;       // G*512*512
  int gh = idx >> 9;
  int c = idx & 511;
  float v = 0.f;
  if (c < 300)      v = Ww[gh * 300 + c];
  else if (c < 350) v = Wt[gh * 50 + (c - 300)];
  else if (c < 400) v = Wr[gh * 50 + (c - 350)];
  Wcat[idx] = f2b(v);
}

// 4 weight matrices in one launch (grid.y selects)
__global__ void cvt_w4(const float* __restrict__ a, const float* __restrict__ b,
                       const float* __restrict__ c, const float* __restrict__ d,
                       unsigned short* oa, unsigned short* ob,
                       unsigned short* oc, unsigned short* od) {
  const float* in; unsigned short* out;
  switch (blockIdx.y) {
    case 0: in = a; out = oa; break;
    case 1: in = b; out = ob; break;
    case 2: in = c; out = oc; break;
    default: in = d; out = od; break;
  }
  int i = (blockIdx.x * 256 + threadIdx.x) * 4;   // 1310720 elems
  float4 v = *(const float4*)(in + i);
  ushort4 o;
  o.x = f2b(v.x); o.y = f2b(v.y); o.z = f2b(v.z); o.w = f2b(v.w);
  *(ushort4*)(out + i) = o;
}

__global__ void cvt_x2(const float* __restrict__ a, const float* __restrict__ b,
                       unsigned short* oa, unsigned short* ob) {
  const float* in = blockIdx.y ? b : a;
  unsigned short* out = blockIdx.y ? ob : oa;
  int i = (blockIdx.x * 256 + threadIdx.x) * 4;   // 8388608 elems
  float4 v = *(const float4*)(in + i);
  ushort4 o;
  o.x = f2b(v.x); o.y = f2b(v.y); o.z = f2b(v.z); o.w = f2b(v.w);
  *(ushort4*)(out + i) = o;
}

__global__ void pack_bias(const float* __restrict__ bw, const float* __restrict__ bt,
                          const float* __restrict__ br, const float* __restrict__ bh,
                          const float* __restrict__ bl, const float* __restrict__ bhp,
                          const float* __restrict__ bk,
                          float* bias0, float* bias1, float* bias2, float* biasD) {
  int i = blockIdx.x * 256 + threadIdx.x;
  if (i < GATES * HDIM) {
    bias0[i] = bw[i] + bt[i] + br[i];
    bias1[i] = bh[i];
    bias2[i] = bl[i];
    biasD[i] = bhp[i] + bk[i];
  }
}

// ---------------- GEMM: 256x256 tile, BK=32, 8 waves, 2-phase/K-tile ---------
// W stacks are [2560][512]; grid (64,10): gcol0 = y*256 -> gate = gcol0>>9.
// Per K-tile: phase p in {0,1}: ds_read A-quadrant (+B in p0) | issue stage
// gloads for tile s+1 | lgkmcnt(0)+sched_barrier | setprio(1) 16 MFMA | barrier.
// Boundary: vmcnt(0) (only tile-s+1 loads outstanding, ~2 phases of cover) +
// barrier. Swizzle: 4 slots/row, phys = slot ^ (row&3) both sides (G21).
// MODE 0: Out = tanh(A*W^T + bias); MODE 1: + A2*W2^T + Madd, gate activation.

template<int MODE>
__global__ __launch_bounds__(512, 2) void gemm_big(
    const unsigned short* __restrict__ A1, const unsigned short* __restrict__ A2,
    const unsigned short* __restrict__ W1, const unsigned short* __restrict__ W2,
    const float* __restrict__ bias,
    const unsigned short* __restrict__ Madd,
    unsigned short* __restrict__ Out,
    int aPerGate)
{
  __shared__ __align__(16) unsigned short Abuf[2][256 * 32];   // 2 x 16 KB
  __shared__ __align__(16) unsigned short Bbuf[2][256 * 32];   // 2 x 16 KB

  const int t = threadIdx.x;
  const int row0  = blockIdx.x * 256;          // N tile
  const int gcol0 = blockIdx.y * 256;          // global col in [0,2560)
  const int g = gcol0 >> 9;
  const size_t aslab = aPerGate ? (size_t)g * NROWS * HDIM : 0;
  const int S = (MODE == 1) ? 32 : 16;         // K-tiles of 32

  const int wid = t >> 6, l = t & 63;
  const int wrow = (wid >> 2) * 128;           // 2 M-warps
  const int wcol = (wid & 3) * 64;             // 4 N-warps
  const int fr = l & 15, q = l >> 4;

  f32x4 acc[8][4];
#pragma unroll
  for (int mi = 0; mi < 8; ++mi)
#pragma unroll
    for (int ni = 0; ni < 4; ++ni)
      acc[mi][ni] = (f32x4){0.f, 0.f, 0.f, 0.f};

  // staging: issue j covers rows j*128+(t>>2), dst shorts = j*4096 + t*8 (linear)
  auto stage = [&](int c, int buf) {
    const unsigned short* Ab; const unsigned short* Wb; int kloc;
    if (MODE == 1 && c >= 16) { Ab = A2;         Wb = W2; kloc = (c - 16) * 32; }
    else                      { Ab = A1 + aslab; Wb = W1; kloc = c * 32; }
#pragma unroll
    for (int j = 0; j < 2; ++j) {
      const int r  = j * 128 + (t >> 2);
      const int sg = ((t & 3) ^ (r & 3)) * 8;
      gload_lds16(Ab + (size_t)(row0 + r) * HDIM + kloc + sg,  &Abuf[buf][j * 4096 + t * 8]);
      gload_lds16(Wb + (size_t)(gcol0 + r) * HDIM + kloc + sg, &Bbuf[buf][j * 4096 + t * 8]);
    }
  };

  stage(0, 0);
  asm volatile("s_waitcnt vmcnt(0)" ::: "memory");
  __builtin_amdgcn_s_barrier();

  bf16x8 bq[4];
  for (int s = 0; s < S; ++s) {
    const int buf = s & 1;
#pragma unroll
    for (int p = 0; p < 2; ++p) {
      bf16x8 af[4];
#pragma unroll
      for (int mi = 0; mi < 4; ++mi) {
        const int r = wrow + (p * 4 + mi) * 16 + fr;
        af[mi] = *reinterpret_cast<const bf16x8*>(&Abuf[buf][r * 32 + ((q ^ (r & 3)) * 8)]);
      }
      if (p == 0) {
#pragma unroll
        for (int ni = 0; ni < 4; ++ni) {
          const int r = wcol + ni * 16 + fr;
          bq[ni] = *reinterpret_cast<const bf16x8*>(&Bbuf[buf][r * 32 + ((q ^ (r & 3)) * 8)]);
        }
        if (s + 1 < S) stage(s + 1, buf ^ 1);   // loads fly under both phases
      }
      asm volatile("s_waitcnt lgkmcnt(0)" ::: "memory");
      __builtin_amdgcn_sched_barrier(0);
      __builtin_amdgcn_s_setprio(1);
#pragma unroll
      for (int mi = 0; mi < 4; ++mi)
#pragma unroll
        for (int ni = 0; ni < 4; ++ni)
          acc[p * 4 + mi][ni] = __builtin_amdgcn_mfma_f32_16x16x32_bf16(af[mi], bq[ni], acc[p * 4 + mi][ni], 0, 0, 0);
      __builtin_amdgcn_s_setprio(0);
      if (p == 0) __builtin_amdgcn_s_barrier();
    }
    // tile boundary: own loads for tile s+1 must be retired before any wave
    // reads buf^1; each thread drains its own, then barrier.
    asm volatile("s_waitcnt vmcnt(0)" ::: "memory");
    __builtin_amdgcn_s_barrier();
  }

  // epilogue: C/D col=lane&15, row=q*4+j  [m89/m91]
  const size_t NM = (size_t)NROWS * HDIM;
  unsigned short* outg = Out + (size_t)g * NM;
  const int colbase = gcol0 & 511;
#pragma unroll
  for (int mi = 0; mi < 8; ++mi) {
#pragma unroll
    for (int ni = 0; ni < 4; ++ni) {
      const int colLoc = colbase + wcol + ni * 16 + fr;
      const float bb = bias[g * HDIM + colLoc];
#pragma unroll
      for (int j = 0; j < 4; ++j) {
        const int nrow = row0 + wrow + mi * 16 + q * 4 + j;
        float v = acc[mi][ni][j] + bb;
        if (MODE == 1) {
          v += b2f(Madd[(size_t)g * NM + (size_t)nrow * HDIM + colLoc]);
          v = (g < 4) ? fast_sigmoid(v) : fast_tanh(v);
        } else {
          v = fast_tanh(v);
        }
        outg[(size_t)nrow * HDIM + colLoc] = f2b(v);
      }
    }
  }
}

// ---------------- final elementwise combine (f32 q/c_prev, f32 out) ---------

__device__ inline float exb(const uint4& v, int j) {
  unsigned int wd = ((const unsigned int*)&v)[j >> 1];
  return b2f((unsigned short)(wd >> ((j & 1) * 16)));
}

__global__ void combine(const unsigned short* __restrict__ gates,
                        const float* __restrict__ q,
                        const float* __restrict__ cp,
                        float* __restrict__ out) {
  const size_t NM = (size_t)NROWS * HDIM;
  size_t i8 = ((size_t)blockIdx.x * 256 + threadIdx.x) * 8;
  if (i8 >= NM) return;
  uint4 gi = *(const uint4*)(gates + 0 * NM + i8);
  uint4 gf = *(const uint4*)(gates + 1 * NM + i8);
  uint4 gl = *(const uint4*)(gates + 2 * NM + i8);
  uint4 go = *(const uint4*)(gates + 3 * NM + i8);
  uint4 gu = *(const uint4*)(gates + 4 * NM + i8);
  float4 q0 = *(const float4*)(q + i8);
  float4 q1 = *(const float4*)(q + i8 + 4);
  float4 p0 = *(const float4*)(cp + i8);
  float4 p1 = *(const float4*)(cp + i8 + 4);
  float qv[8] = {q0.x, q0.y, q0.z, q0.w, q1.x, q1.y, q1.z, q1.w};
  float pv[8] = {p0.x, p0.y, p0.z, p0.w, p1.x, p1.y, p1.z, p1.w};
  float hv[8], cv[8];
#pragma unroll
  for (int j = 0; j < 8; ++j) {
    float c = exb(gi, j) * exb(gu, j) + exb(gf, j) * qv[j] + exb(gl, j) * pv[j];
    hv[j] = exb(go, j) * fast_tanh(c);
    cv[j] = c;
  }
  *(float4*)(out + i8)      = make_float4(hv[0], hv[1], hv[2], hv[3]);
  *(float4*)(out + i8 + 4)  = make_float4(hv[4], hv[5], hv[6], hv[7]);
  *(float4*)(out + NM + i8)     = make_float4(cv[0], cv[1], cv[2], cv[3]);
  *(float4*)(out + NM + i8 + 4) = make_float4(cv[4], cv[5], cv[6], cv[7]);
}

// ---------------- launch ----------------

extern "C" void kernel_launch(void* const* d_in, const int* in_sizes, int n_in,
                              void* d_out, int out_size, void* d_ws, size_t ws_size,
                              hipStream_t stream) {
  const float* word  = (const float*)d_in[0];
  const float* tag   = (const float*)d_in[1];
  const float* rel   = (const float*)d_in[2];
  const float* kin   = (const float*)d_in[3];
  const float* qin   = (const float*)d_in[4];
  const float* hprev = (const float*)d_in[5];
  const float* cprev = (const float*)d_in[6];
  const float* Ww    = (const float*)d_in[7];
  const float* bw    = (const float*)d_in[8];
  const float* Wt    = (const float*)d_in[9];
  const float* bt    = (const float*)d_in[10];
  const float* Wr    = (const float*)d_in[11];
  const float* br    = (const float*)d_in[12];
  const float* Wh    = (const float*)d_in[13];
  const float* bh    = (const float*)d_in[14];
  const float* Wl    = (const float*)d_in[15];
  const float* bl    = (const float*)d_in[16];
  const float* Whp   = (const float*)d_in[17];
  const float* bhp   = (const float*)d_in[18];
  const float* Wk    = (const float*)d_in[19];
  const float* bk    = (const float*)d_in[20];

  char* ws = (char*)d_ws;
  unsigned short* xcat   = (unsigned short*)(ws);                 // 16,777,216 B
  unsigned short* Wcat   = (unsigned short*)(ws + 16777216);      //  2,621,440 B
  unsigned short* Whb    = (unsigned short*)(ws + 19398656);
  unsigned short* Wlb    = (unsigned short*)(ws + 22020096);
  unsigned short* Whpb   = (unsigned short*)(ws + 24641536);
  unsigned short* Wkb    = (unsigned short*)(ws + 27262976);
  unsigned short* hprevb = (unsigned short*)(ws + 29884416);      // 16,777,216 B
  unsigned short* kb16   = (unsigned short*)(ws + 46661632);      // 16,777,216 B
  float* bias0           = (float*)(ws + 63438848);
  float* bias1           = (float*)(ws + 63449088);
  float* bias2           = (float*)(ws + 63459328);
  float* biasD           = (float*)(ws + 63469568);
  unsigned short* bufA   = (unsigned short*)(ws + 63479808);      // 83,886,080 B
  unsigned short* bufB   = (unsigned short*)(ws + 147365888);     // 83,886,080 B

  pack_x<<<32768, 256, 0, stream>>>(word, tag, rel, xcat);
  pack_w<<<5120, 256, 0, stream>>>(Ww, Wt, Wr, Wcat);
  cvt_w4<<<dim3(1280, 4), 256, 0, stream>>>(Wh, Wl, Whp, Wk, Whb, Wlb, Whpb, Wkb);
  cvt_x2<<<dim3(8192, 2), 256, 0, stream>>>(hprev, kin, hprevb, kb16);
  pack_bias<<<10, 256, 0, stream>>>(bw, bt, br, bh, bl, bhp, bk, bias0, bias1, bias2, biasD);

  dim3 grid(NROWS / 256, (GATES * HDIM) / 256);   // 64 x 10
  // h0 = tanh(xcat W0^T + b0)
  gemm_big<0><<<grid, 512, 0, stream>>>(xcat, nullptr, Wcat, nullptr, bias0, nullptr, bufA, 0);
  // h1 = tanh(h0 Whid^T + bhid)
  gemm_big<0><<<grid, 512, 0, stream>>>(bufA, nullptr, Whb, nullptr, bias1, nullptr, bufB, 1);
  // m = tanh(h1 Wlast^T + blast)
  gemm_big<0><<<grid, 512, 0, stream>>>(bufB, nullptr, Wlb, nullptr, bias2, nullptr, bufA, 1);
  // gates = act(hprev Whp^T + k Wk^T + biases + m)
  gemm_big<1><<<grid, 512, 0, stream>>>(hprevb, kb16, Whpb, Wkb, biasD, bufA, bufB, 0);
  // c = i*u + f_down*q + f_left*c_prev ; h = o*tanh(c)
  combine<<<4096, 256, 0, stream>>>(bufB, qin, cprev, (float*)d_out);
}